// Round 7
// baseline (382.920 us; speedup 1.0000x reference)
//
#include <hip/hip_runtime.h>

#define Bc 16
#define Cc 128
#define Nc 32768
#define Sc 100
#define CHUNK 1024
#define BLOCK 256
#define SPAD 129               // padded segment stride: bank = (s + c) % 32
#define MONO_NEG_INF 0x007FFFFFu

// Order-preserving fp32 -> uint32 mapping (monotonic for all non-NaN values).
__device__ __forceinline__ unsigned enc(float f) {
    unsigned u = __float_as_uint(f);
    unsigned m = (unsigned)((int)u >> 31);        // all-ones if negative
    return u ^ (m | 0x80000000u);
}
__device__ __forceinline__ float dec(unsigned v) {
    unsigned m = ~(unsigned)((int)v >> 31);       // all-ones if high bit clear
    return __uint_as_float(v ^ (m | 0x80000000u));
}

__global__ void init_kernel(unsigned* __restrict__ out_u, int n) {
    int i = blockIdx.x * blockDim.x + threadIdx.x;
    if (i < n) out_u[i] = MONO_NEG_INF;
}

__global__ __launch_bounds__(BLOCK) void seg_max_kernel(
        const float* __restrict__ pf, const int* __restrict__ ids,
        unsigned* __restrict__ out_u) {
    __shared__ unsigned acc[Sc * SPAD];           // 51,600 B
    const int tid = threadIdx.x;
    const int chunk = blockIdx.x;                 // 0..31
    const int b = blockIdx.y;                     // 0..15
    const int n0 = chunk * CHUNK;

    for (int i = tid; i < Sc * SPAD; i += BLOCK) acc[i] = MONO_NEG_INF;

    // Each thread owns 4 consecutive points; ids live in registers all loop.
    const int4 id4 = reinterpret_cast<const int4*>(ids + (size_t)b * Nc + n0)[tid];
    const int o0 = id4.x * SPAD;
    const int o1 = id4.y * SPAD;
    const int o2 = id4.z * SPAD;
    const int o3 = id4.w * SPAD;

    __syncthreads();

    const float* base = pf + (size_t)b * Cc * Nc + n0;
    #pragma unroll 4
    for (int c = 0; c < Cc; ++c) {
        float4 v = reinterpret_cast<const float4*>(base + (size_t)c * Nc)[tid];
        atomicMax(&acc[o0 + c], enc(v.x));        // ds_max_u32, no return
        atomicMax(&acc[o1 + c], enc(v.y));
        atomicMax(&acc[o2 + c], enc(v.z));
        atomicMax(&acc[o3 + c], enc(v.w));
    }

    __syncthreads();

    // Merge block-local maxima into global accumulator (device-scope umax).
    unsigned* out_b = out_u + (size_t)b * Sc * Cc;
    for (int i = tid; i < Sc * Cc; i += BLOCK) {
        int s = i >> 7, c = i & 127;
        unsigned v = acc[s * SPAD + c];
        if (v != MONO_NEG_INF) atomicMax(&out_b[i], v);
    }
}

__global__ void convert_kernel(unsigned* __restrict__ out_u, int n) {
    int i = blockIdx.x * blockDim.x + threadIdx.x;
    if (i < n) {
        float f = dec(out_u[i]);
        reinterpret_cast<float*>(out_u)[i] = f;
    }
}

extern "C" void kernel_launch(void* const* d_in, const int* in_sizes, int n_in,
                              void* d_out, int out_size, void* d_ws, size_t ws_size,
                              hipStream_t stream) {
    const float* pf = (const float*)d_in[0];
    const int* ids = (const int*)d_in[1];
    unsigned* out_u = (unsigned*)d_out;

    const int n = Bc * Sc * Cc;                   // 204,800 == out_size
    init_kernel<<<(n + 255) / 256, 256, 0, stream>>>(out_u, n);

    dim3 grid(Nc / CHUNK, Bc);
    seg_max_kernel<<<grid, BLOCK, 0, stream>>>(pf, ids, out_u);

    convert_kernel<<<(n + 255) / 256, 256, 0, stream>>>(out_u, n);
}

// Round 8
// 379.532 us; speedup vs baseline: 1.0089x; 1.0089x over previous
//
#include <hip/hip_runtime.h>

#define Bc 16
#define Cc 128
#define Nc 32768
#define Sc 100
#define NCHUNK 32
#define CHUNK 1024
#define BLOCK 256
#define SPAD 129               // padded segment stride: bank = (s + c) % 32
#define PART (Sc * Cc)         // 12800 elements per (b, chunk) partial
#define MONO_NEG_INF 0x007FFFFFu

// Order-preserving fp32 -> uint32 mapping (monotonic for all non-NaN values).
__device__ __forceinline__ unsigned enc(float f) {
    unsigned u = __float_as_uint(f);
    unsigned m = (unsigned)((int)u >> 31);        // all-ones if negative
    return u ^ (m | 0x80000000u);
}
__device__ __forceinline__ float dec(unsigned v) {
    unsigned m = ~(unsigned)((int)v >> 31);       // all-ones if high bit clear
    return __uint_as_float(v ^ (m | 0x80000000u));
}

// Kernel A: per-(batch, 1024-pt chunk) LDS segment-max, write uint partial.
__global__ __launch_bounds__(BLOCK) void seg_part_kernel(
        const float* __restrict__ pf, const int* __restrict__ ids,
        unsigned* __restrict__ parts) {
    __shared__ unsigned acc[Sc * SPAD];           // 51,600 B -> 3 blocks/CU max
    const int tid = threadIdx.x;
    const int chunk = blockIdx.x;                 // 0..31
    const int b = blockIdx.y;                     // 0..15
    const int n0 = chunk * CHUNK;

    for (int i = tid; i < Sc * SPAD; i += BLOCK) acc[i] = MONO_NEG_INF;

    // Each thread owns 4 consecutive points; ids live in registers all loop.
    const int4 id4 = reinterpret_cast<const int4*>(ids + (size_t)b * Nc + n0)[tid];
    const int o0 = id4.x * SPAD;
    const int o1 = id4.y * SPAD;
    const int o2 = id4.z * SPAD;
    const int o3 = id4.w * SPAD;

    __syncthreads();

    const float* base = pf + (size_t)b * Cc * Nc + n0;
    #pragma unroll 8
    for (int c = 0; c < Cc; ++c) {
        float4 v = reinterpret_cast<const float4*>(base + (size_t)c * Nc)[tid];
        atomicMax(&acc[o0 + c], enc(v.x));        // ds_max_u32, no return
        atomicMax(&acc[o1 + c], enc(v.y));
        atomicMax(&acc[o2 + c], enc(v.z));
        atomicMax(&acc[o3 + c], enc(v.w));
    }

    __syncthreads();

    // Coalesced partial store: parts[(b*NCHUNK + chunk)][s*128 + c].
    unsigned* dst = parts + (size_t)(b * NCHUNK + chunk) * PART;
    for (int i = tid; i < PART; i += BLOCK)
        dst[i] = acc[(i >> 7) * SPAD + (i & 127)];
}

// Kernel B: reduce 32 partials per output element, decode, write fp32.
__global__ __launch_bounds__(BLOCK) void seg_reduce_kernel(
        const unsigned* __restrict__ parts, float* __restrict__ out) {
    const int t = blockIdx.x * BLOCK + threadIdx.x;   // 0..51199
    const int e0 = t * 4;                             // 4 consecutive outputs
    const int b = e0 / PART;                          // PART % 4 == 0: same b
    const int r = e0 % PART;

    const unsigned* p = parts + (size_t)b * NCHUNK * PART + r;
    unsigned mx = MONO_NEG_INF, my = MONO_NEG_INF,
             mz = MONO_NEG_INF, mw = MONO_NEG_INF;
    #pragma unroll
    for (int k = 0; k < NCHUNK; ++k) {
        uint4 v = *reinterpret_cast<const uint4*>(p + (size_t)k * PART);
        mx = v.x > mx ? v.x : mx;
        my = v.y > my ? v.y : my;
        mz = v.z > mz ? v.z : mz;
        mw = v.w > mw ? v.w : mw;
    }
    float4 o = { dec(mx), dec(my), dec(mz), dec(mw) };
    *reinterpret_cast<float4*>(out + e0) = o;
}

extern "C" void kernel_launch(void* const* d_in, const int* in_sizes, int n_in,
                              void* d_out, int out_size, void* d_ws, size_t ws_size,
                              hipStream_t stream) {
    const float* pf = (const float*)d_in[0];
    const int* ids = (const int*)d_in[1];
    float* out = (float*)d_out;
    unsigned* parts = (unsigned*)d_ws;            // 512 * 12800 * 4 = 26.2 MB

    dim3 gridA(NCHUNK, Bc);
    seg_part_kernel<<<gridA, BLOCK, 0, stream>>>(pf, ids, parts);

    const int n = Bc * PART;                      // 204,800 outputs
    seg_reduce_kernel<<<(n / 4) / BLOCK, BLOCK, 0, stream>>>(parts, out);
}

// Round 9
// 367.721 us; speedup vs baseline: 1.0413x; 1.0321x over previous
//
#include <hip/hip_runtime.h>

#define Bc 16
#define Cc 128
#define Nc 32768
#define NCHUNK 32
#define CHUNK 1024
#define BLOCK 256
#define Sc 100
#define CP 64                  // channels per block (2 blocks cover 128)
#define CPAD 65                // bank = (s*65 + c) % 32 = (s + c) % 32
#define PART (Sc * Cc)         // 12800 elements per (b, chunk) partial
#define MONO_NEG_INF 0x007FFFFFu

// Order-preserving fp32 -> uint32 mapping (monotonic for all non-NaN values).
__device__ __forceinline__ unsigned enc(float f) {
    unsigned u = __float_as_uint(f);
    unsigned m = (unsigned)((int)u >> 31);        // all-ones if negative
    return u ^ (m | 0x80000000u);
}
__device__ __forceinline__ float dec(unsigned v) {
    unsigned m = ~(unsigned)((int)v >> 31);       // all-ones if high bit clear
    return __uint_as_float(v ^ (m | 0x80000000u));
}

// Kernel A: per-(chunk, batch, channel-half) LDS segment-max -> uint partial.
// LDS = 100*65*4 = 26,000 B -> 6 blocks/CU cap; grid 1024 -> 4 blocks/CU.
__global__ __launch_bounds__(BLOCK) void seg_part_kernel(
        const float* __restrict__ pf, const int* __restrict__ ids,
        unsigned* __restrict__ parts) {
    __shared__ unsigned acc[Sc * CPAD];
    const int tid = threadIdx.x;
    const int chunk = blockIdx.x;                 // 0..31
    const int b = blockIdx.y;                     // 0..15
    const int cp = blockIdx.z;                    // 0..1
    const int n0 = chunk * CHUNK;
    const int c0 = cp * CP;

    for (int i = tid; i < Sc * CPAD; i += BLOCK) acc[i] = MONO_NEG_INF;

    // Each thread owns 4 consecutive points; ids live in registers all loop.
    const int4 id4 = reinterpret_cast<const int4*>(ids + (size_t)b * Nc + n0)[tid];
    const int o0 = id4.x * CPAD;
    const int o1 = id4.y * CPAD;
    const int o2 = id4.z * CPAD;
    const int o3 = id4.w * CPAD;

    __syncthreads();

    const float* base = pf + (size_t)b * Cc * Nc + (size_t)c0 * Nc + n0;
    #pragma unroll 8
    for (int c = 0; c < CP; ++c) {
        float4 v = reinterpret_cast<const float4*>(base + (size_t)c * Nc)[tid];
        atomicMax(&acc[o0 + c], enc(v.x));        // ds_max_u32, no return
        atomicMax(&acc[o1 + c], enc(v.y));
        atomicMax(&acc[o2 + c], enc(v.z));
        atomicMax(&acc[o3 + c], enc(v.w));
    }

    __syncthreads();

    // Coalesced-ish partial store: parts[(b,chunk)][s*128 + c0 + c].
    unsigned* dst = parts + (size_t)(b * NCHUNK + chunk) * PART + c0;
    for (int i = tid; i < Sc * CP; i += BLOCK) {
        int s = i / CP, c = i % CP;
        dst[s * Cc + c] = acc[s * CPAD + c];
    }
}

// Kernel B: reduce 32 partials per output element, decode, write fp32.
__global__ __launch_bounds__(BLOCK) void seg_reduce_kernel(
        const unsigned* __restrict__ parts, float* __restrict__ out) {
    const int t = blockIdx.x * BLOCK + threadIdx.x;   // 0..51199
    const int e0 = t * 4;                             // 4 consecutive outputs
    const int b = e0 / PART;                          // PART % 4 == 0: same b
    const int r = e0 % PART;

    const unsigned* p = parts + (size_t)b * NCHUNK * PART + r;
    unsigned mx = MONO_NEG_INF, my = MONO_NEG_INF,
             mz = MONO_NEG_INF, mw = MONO_NEG_INF;
    #pragma unroll
    for (int k = 0; k < NCHUNK; ++k) {
        uint4 v = *reinterpret_cast<const uint4*>(p + (size_t)k * PART);
        mx = v.x > mx ? v.x : mx;
        my = v.y > my ? v.y : my;
        mz = v.z > mz ? v.z : mz;
        mw = v.w > mw ? v.w : mw;
    }
    float4 o = { dec(mx), dec(my), dec(mz), dec(mw) };
    *reinterpret_cast<float4*>(out + e0) = o;
}

extern "C" void kernel_launch(void* const* d_in, const int* in_sizes, int n_in,
                              void* d_out, int out_size, void* d_ws, size_t ws_size,
                              hipStream_t stream) {
    const float* pf = (const float*)d_in[0];
    const int* ids = (const int*)d_in[1];
    float* out = (float*)d_out;
    unsigned* parts = (unsigned*)d_ws;            // 512 * 12800 * 4 = 26.2 MB

    dim3 gridA(NCHUNK, Bc, 2);
    seg_part_kernel<<<gridA, BLOCK, 0, stream>>>(pf, ids, parts);

    const int n = Bc * PART;                      // 204,800 outputs
    seg_reduce_kernel<<<(n / 4) / BLOCK, BLOCK, 0, stream>>>(parts, out);
}